// Round 4
// baseline (190.540 us; speedup 1.0000x reference)
//
#include <hip/hip_runtime.h>

// Problem instance constants (from reference setup_inputs): B=64, S=131072, C=3.
#define BB 64
#define SS 131072
#define WIN 100
#define TILE 2048           // positions per block (S % TILE == 0 -> 64 tiles/row)
#define NTHREADS 256
#define NBLOCKS (BB * (SS / TILE))               // 4096
#define EXT (TILE + 2*WIN)                       // 2248 extended-target region
#define NITER ((EXT + NTHREADS - 1) / NTHREADS)  // 9
#define NWORDS ((EXT + 63) / 64)                 // 36 u64 pos-flag words

// Workspace: per-block slot of 4 doubles (no atomics, no memset needed):
//   slot[blk] = { masked_sum, masked_cnt, tile_unmasked_sum, tile_pos_cnt }
__global__ __launch_bounds__(NTHREADS) void focal_main(
    const float* __restrict__ inputs, const int* __restrict__ targets,
    const float* __restrict__ alpha, double* __restrict__ slots)
{
    __shared__ unsigned char sh_t[EXT];          // target class per ext position
    __shared__ unsigned long long wbits[NWORDS]; // bit i = (target[ext_lo+i] > 0)
    __shared__ unsigned long long mbits[NWORDS]; // wbits dilated by +/-WIN
    __shared__ double red[(NTHREADS/64) * 4];

    const int t = threadIdx.x;
    const int b = blockIdx.x >> 6;        // 64 tiles per row
    const int tile = blockIdx.x & 63;
    const int s0 = tile * TILE;           // row-local tile start
    const int ext_lo = (s0 - WIN > 0) ? (s0 - WIN) : 0;
    const int ext_hi = (s0 + TILE + WIN < SS) ? (s0 + TILE + WIN) : SS;
    const int ext_len = ext_hi - ext_lo;

    // ---- prefetch ALL input data for this thread into registers FIRST ----
    const float* inrow = inputs + (long)b * SS * 3;
    const int p0 = s0 + t * 4;                  // 4 consecutive positions
    const int p1 = s0 + (NTHREADS + t) * 4;     // second group
    const float4* ip0 = (const float4*)(inrow + (long)p0 * 3); // 48B aligned
    const float4* ip1 = (const float4*)(inrow + (long)p1 * 3);
    const float4 q0 = ip0[0], q1 = ip0[1], q2 = ip0[2];
    const float4 q3 = ip1[0], q4 = ip1[1], q5 = ip1[2];

    // ---- stage targets; build pos bitmask via wave ballots (NO scan) ----
    const int* trow = targets + (long)b * SS;
    const int wave = t >> 6, lane = t & 63;
    const int tr_lo = s0 - ext_lo;          // ext-local start of exclusive tile
    int cnt_p = 0;                          // positives in exclusive tile region
    #pragma unroll
    for (int it = 0; it < NITER; ++it) {
        const int k = it * NTHREADS + t;
        const int tv = (k < ext_len) ? trow[ext_lo + k] : 0;
        if (k < ext_len) sh_t[k] = (unsigned char)tv;
        const bool pos = (tv > 0);
        cnt_p += (pos && k >= tr_lo && k < tr_lo + TILE) ? 1 : 0;
        const unsigned long long bal = __ballot(pos);
        if (lane == 0) wbits[it * 4 + wave] = bal;
    }
    __syncthreads();

    // ---- dilate bitmask by +/-WIN (wave 0 only; words live in lanes) ----
    // Doubling dilation: shift seq 1,2,4,8,16,32,37 -> exact radius 100.
    if (wave == 0) {
        unsigned long long x = (lane < NWORDS) ? wbits[lane] : 0ULL;
        const int shifts[7] = {1, 2, 4, 8, 16, 32, 37};
        #pragma unroll
        for (int s_i = 0; s_i < 7; ++s_i) {
            const int s = shifts[s_i];
            unsigned long long up = __shfl_up(x, 1);    // word k-1
            if (lane == 0) up = 0ULL;
            unsigned long long dn = __shfl_down(x, 1);  // word k+1 (lane63->junk,
            if (lane == 63) dn = 0ULL;                  //  but lanes>=36 hold 0)
            x = x | (x << s) | (up >> (64 - s)) | (x >> s) | (dn << (64 - s));
        }
        if (lane < NWORDS) mbits[lane] = x;
    }
    __syncthreads();

    // ---- main compute: 4 consecutive positions x 2 groups per thread ----
    const float a0 = alpha[0], a1 = alpha[1], a2 = alpha[2];
    float fsum_m = 0.0f, fsum_a = 0.0f;
    int cnt_m = 0;

    const float xs[24] = {q0.x, q0.y, q0.z, q0.w, q1.x, q1.y, q1.z, q1.w,
                          q2.x, q2.y, q2.z, q2.w, q3.x, q3.y, q3.z, q3.w,
                          q4.x, q4.y, q4.z, q4.w, q5.x, q5.y, q5.z, q5.w};

    #pragma unroll
    for (int g = 0; g < 2; ++g) {
        const int p = (g == 0) ? p0 : p1;
        const int j0 = p - ext_lo;                     // ext-local, %4==0
        // all 4 positions' mask bits live in ONE word (j0%4==0 -> j0%64<=60)
        const unsigned long long mw = mbits[j0 >> 6];
        // 4 packed target bytes in one aligned LDS word
        const unsigned int tpack = *(const unsigned int*)(sh_t + j0);
        #pragma unroll
        for (int j = 0; j < 4; ++j) {
            const float x0 = xs[g*12 + 3*j], x1 = xs[g*12 + 3*j + 1],
                        x2 = xs[g*12 + 3*j + 2];
            const int tv = (tpack >> (8 * j)) & 0xFF;
            const float mx = fmaxf(x0, fmaxf(x1, x2));
            const float e0 = __expf(x0 - mx), e1 = __expf(x1 - mx), e2 = __expf(x2 - mx);
            const float sum = e0 + e1 + e2;
            const float xt  = (tv == 0) ? x0 : ((tv == 1) ? x1 : x2);
            const float et  = (tv == 0) ? e0 : ((tv == 1) ? e1 : e2);
            const float ce  = __logf(sum) + (mx - xt);
            const float pt  = et * __frcp_rn(sum);
            const float w   = (tv == 0) ? a0 : ((tv == 1) ? a1 : a2);
            const float om  = 1.0f - pt;
            const float focal = w * om * om * ce;
            const bool  m   = (mw >> ((j0 & 63) + j)) & 1ULL;

            fsum_a += focal;
            fsum_m += m ? focal : 0.0f;
            cnt_m  += m ? 1 : 0;
        }
    }

    // ---- block reduce (float/int shuffles) + ONE plain store per block ----
    #pragma unroll
    for (int off = 32; off >= 1; off >>= 1) {
        fsum_m += __shfl_down(fsum_m, off);
        fsum_a += __shfl_down(fsum_a, off);
        cnt_m  += __shfl_down(cnt_m, off);
        cnt_p  += __shfl_down(cnt_p, off);
    }
    if (lane == 0) {
        red[wave*4]   = (double)fsum_m; red[wave*4+1] = (double)cnt_m;
        red[wave*4+2] = (double)fsum_a; red[wave*4+3] = (double)cnt_p;
    }
    __syncthreads();
    if (t == 0) {
        double sm = 0, sc = 0, sa = 0, sp = 0;
        #pragma unroll
        for (int w = 0; w < NTHREADS/64; ++w) {
            sm += red[w*4]; sc += red[w*4+1]; sa += red[w*4+2]; sp += red[w*4+3];
        }
        double* slot = slots + (long)blockIdx.x * 4;
        slot[0] = sm;
        slot[1] = sc;
        slot[2] = sa;
        slot[3] = sp;
    }
}

__global__ __launch_bounds__(NTHREADS) void focal_final(
    const double* __restrict__ slots, float* __restrict__ out)
{
    __shared__ double red[(NTHREADS/64) * 2];
    __shared__ double tot[2];
    const int t = threadIdx.x;
    const int wave = t >> 6, lane = t & 63;

    // Phase A: global masked sum/count over all 4096 slots
    double sm = 0.0, sc = 0.0;
    for (int k = t; k < NBLOCKS; k += NTHREADS) {
        sm += slots[(long)k * 4 + 0];
        sc += slots[(long)k * 4 + 1];
    }
    #pragma unroll
    for (int off = 32; off >= 1; off >>= 1) {
        sm += __shfl_down(sm, off);
        sc += __shfl_down(sc, off);
    }
    if (lane == 0) { red[wave*2] = sm; red[wave*2+1] = sc; }
    __syncthreads();
    if (t == 0) {
        double a = 0, b = 0;
        #pragma unroll
        for (int w = 0; w < NTHREADS/64; ++w) { a += red[w*2]; b += red[w*2+1]; }
        tot[0] = a; tot[1] = b;
    }
    __syncthreads();

    // Phase B: per-row "no positives" correction (wave 0, thread t = row t)
    double corr_s = 0.0, corr_c = 0.0;
    if (t < BB) {
        double row_sum = 0.0, row_pos = 0.0;
        for (int j = 0; j < 64; ++j) {
            const long blk = (long)t * 64 + j;
            row_sum += slots[blk * 4 + 2];
            row_pos += slots[blk * 4 + 3];
        }
        if (row_pos == 0.0) { corr_s = row_sum; corr_c = (double)SS; }
    }
    if (wave == 0) {
        #pragma unroll
        for (int off = 32; off >= 1; off >>= 1) {
            corr_s += __shfl_down(corr_s, off);
            corr_c += __shfl_down(corr_c, off);
        }
        if (t == 0) {
            const double total = tot[0] + corr_s;
            const double count = tot[1] + corr_c;
            out[0] = (float)(total / count);
        }
    }
}

extern "C" void kernel_launch(void* const* d_in, const int* in_sizes, int n_in,
                              void* d_out, int out_size, void* d_ws, size_t ws_size,
                              hipStream_t stream) {
    const float* inputs  = (const float*)d_in[0];
    const int*   targets = (const int*)d_in[1];
    const float* alpha   = (const float*)d_in[2];
    float* out = (float*)d_out;

    double* slots = (double*)d_ws;   // NBLOCKS * 4 doubles = 128 KB, all written

    focal_main<<<NBLOCKS, NTHREADS, 0, stream>>>(inputs, targets, alpha, slots);
    focal_final<<<1, NTHREADS, 0, stream>>>(slots, out);
}

// Round 5
// 178.948 us; speedup vs baseline: 1.0648x; 1.0648x over previous
//
#include <hip/hip_runtime.h>

// Problem instance constants (from reference setup_inputs): B=64, S=131072, C=3.
#define BB 64
#define SS 131072
#define WIN 100
#define TILE 4096           // positions per block
#define NTHREADS 256
#define TILES_PER_ROW (SS / TILE)            // 32
#define NBLOCKS (BB * TILES_PER_ROW)         // 2048 = exactly 8 blocks/CU
#define EXT (TILE + 2*WIN)                   // 4296 ext-target region
#define NWORDS ((EXT + 63) / 64)             // 68 u64 pos-flag words
#define SH_BYTES (NWORDS * 64)               // 4352 (zero-padded past ext_len)
#define K4TOT (SH_BYTES / 4)                 // 1088 packed-u32 stores
#define SROUNDS ((K4TOT + NTHREADS - 1) / NTHREADS)  // 5
#define NGROUPS (TILE / (NTHREADS * 4))      // 4 float4-groups per thread

// Workspace: per-block slot of 4 doubles (no atomics, no memset needed):
//   slot[blk] = { masked_sum, masked_cnt, tile_unmasked_sum, tile_pos_cnt }
__global__ __launch_bounds__(NTHREADS, 8) void focal_main(
    const float* __restrict__ inputs, const int* __restrict__ targets,
    const float* __restrict__ alpha, double* __restrict__ slots)
{
    __shared__ __align__(16) unsigned char sh_t[SH_BYTES]; // target class bytes
    __shared__ unsigned long long wbits[NWORDS]; // bit i = (target[ext_lo+i]>0)
    __shared__ unsigned long long mbits[NWORDS]; // wbits dilated by +/-WIN
    __shared__ double red[(NTHREADS/64) * 4];

    const int t = threadIdx.x;
    const int b = blockIdx.x / TILES_PER_ROW;
    const int tile = blockIdx.x % TILES_PER_ROW;
    const int s0 = tile * TILE;           // row-local tile start
    const int ext_lo = (s0 - WIN > 0) ? (s0 - WIN) : 0;
    const int ext_hi = (s0 + TILE + WIN < SS) ? (s0 + TILE + WIN) : SS;
    const int ext_len = ext_hi - ext_lo;  // always % 4 == 0 here
    const int tr_lo = s0 - ext_lo;        // ext-local start of exclusive tile

    // ---- issue group-0 input loads FIRST (overlap with all staging) ----
    const float* inrow = inputs + (long)b * SS * 3;
    const float4* gp0 = (const float4*)(inrow + (long)(s0 + t * 4) * 3);
    float4 c0 = gp0[0], c1 = gp0[1], c2 = gp0[2];

    // ---- stage targets as packed bytes via int4 loads (zero-pad tail) ----
    const int* trow = targets + (long)b * SS;
    #pragma unroll
    for (int it = 0; it < SROUNDS; ++it) {
        const int k4 = it * NTHREADS + t;           // u32 slot in sh_t
        if (k4 < K4TOT) {
            unsigned int pk = 0;
            if (4 * k4 < ext_len) {                 // ext_len%4==0 -> full int4
                const int4 tv4 = *(const int4*)(trow + ext_lo + 4 * k4);
                pk = (unsigned)(tv4.x & 3) | ((unsigned)(tv4.y & 3) << 8) |
                     ((unsigned)(tv4.z & 3) << 16) | ((unsigned)(tv4.w & 3) << 24);
            }
            ((unsigned int*)sh_t)[k4] = pk;
        }
    }
    __syncthreads();

    // ---- build wbits: one u64 word per thread (t < 68), from LDS bytes ----
    int cnt_p = 0;                          // positives in exclusive tile region
    if (t < NWORDS) {
        const uint4* qp = (const uint4*)(sh_t + (t << 6));
        unsigned long long wv = 0;
        #pragma unroll
        for (int r = 0; r < 4; ++r) {
            const uint4 u = qp[r];
            unsigned int x, nz;
            x = u.x; nz = (x | (x >> 1)) & 0x01010101u;
            wv |= (unsigned long long)((nz * 0x01020408u) >> 24) << (r*16 + 0);
            x = u.y; nz = (x | (x >> 1)) & 0x01010101u;
            wv |= (unsigned long long)((nz * 0x01020408u) >> 24) << (r*16 + 4);
            x = u.z; nz = (x | (x >> 1)) & 0x01010101u;
            wv |= (unsigned long long)((nz * 0x01020408u) >> 24) << (r*16 + 8);
            x = u.w; nz = (x | (x >> 1)) & 0x01010101u;
            wv |= (unsigned long long)((nz * 0x01020408u) >> 24) << (r*16 + 12);
        }
        wbits[t] = wv;
        // positives inside [tr_lo, tr_lo+TILE) restricted to this word
        int lo_bit = tr_lo - (t << 6);        if (lo_bit < 0) lo_bit = 0;
        int hi_bit = tr_lo + TILE - (t << 6); if (hi_bit > 64) hi_bit = 64;
        if (hi_bit > lo_bit) {
            unsigned long long rm = (hi_bit >= 64) ? ~0ULL : ((1ULL << hi_bit) - 1);
            rm &= (~0ULL << lo_bit);
            cnt_p = __popcll(wv & rm);
        }
    }
    __syncthreads();

    // ---- exact closed-form dilation by +/-100 per word (t < 68) ----
    // result word w gets: c(w): all bits if nonzero (63 < 100);
    //   d=w+1: j >= ctz(d)-36;  e=w+2: j >= ctz(e)+28;
    //   b=w-1: j <= msb(b)+36;  a=w-2: j <= msb(a)-28.
    if (t < NWORDS) {
        const unsigned long long a = (t >= 2) ? wbits[t-2] : 0ULL;
        const unsigned long long bw = (t >= 1) ? wbits[t-1] : 0ULL;
        const unsigned long long c = wbits[t];
        const unsigned long long d = (t+1 < NWORDS) ? wbits[t+1] : 0ULL;
        const unsigned long long e = (t+2 < NWORDS) ? wbits[t+2] : 0ULL;
        unsigned long long m = c ? ~0ULL : 0ULL;
        if (d) { const int lo = __builtin_ctzll(d) - 36;
                 m |= (lo <= 0) ? ~0ULL : (~0ULL << lo); }
        if (e) { const int lo = __builtin_ctzll(e) + 28;
                 if (lo <= 63) m |= (~0ULL << lo); }
        if (bw) { const int hi = 63 - __builtin_clzll(bw) + 36;
                  m |= (hi >= 63) ? ~0ULL : (~0ULL >> (63 - hi)); }
        if (a) { const int hi = 63 - __builtin_clzll(a) - 28;
                 if (hi >= 0) m |= (hi >= 63) ? ~0ULL : (~0ULL >> (63 - hi)); }
        mbits[t] = m;
    }
    __syncthreads();

    // ---- main compute: software-pipelined groups of 4 positions ----
    const float a0 = alpha[0], a1 = alpha[1], a2 = alpha[2];
    float fsum_m = 0.0f, fsum_a = 0.0f;
    int cnt_m = 0;

    #pragma unroll
    for (int g = 0; g < NGROUPS; ++g) {
        float4 n0, n1, n2;
        if (g + 1 < NGROUPS) {               // prefetch next group while computing
            const float4* gpn =
                (const float4*)(inrow + (long)(s0 + ((g+1)*NTHREADS + t) * 4) * 3);
            n0 = gpn[0]; n1 = gpn[1]; n2 = gpn[2];
        }
        const int p = s0 + (g*NTHREADS + t) * 4;
        const int j0 = p - ext_lo;                          // %4==0
        const unsigned long long mw = mbits[j0 >> 6];       // 4 bits in one word
        const unsigned int tpack = *(const unsigned int*)(sh_t + j0);
        const float xs[12] = {c0.x, c0.y, c0.z, c0.w, c1.x, c1.y, c1.z, c1.w,
                              c2.x, c2.y, c2.z, c2.w};
        #pragma unroll
        for (int j = 0; j < 4; ++j) {
            const float x0 = xs[3*j], x1 = xs[3*j+1], x2 = xs[3*j+2];
            const int tv = (tpack >> (8 * j)) & 0xFF;
            const float mx = fmaxf(x0, fmaxf(x1, x2));
            const float e0 = __expf(x0 - mx), e1 = __expf(x1 - mx), e2 = __expf(x2 - mx);
            const float sum = e0 + e1 + e2;
            const float xt  = (tv == 0) ? x0 : ((tv == 1) ? x1 : x2);
            const float et  = (tv == 0) ? e0 : ((tv == 1) ? e1 : e2);
            const float ce  = __logf(sum) + (mx - xt);
            const float pt  = et * __frcp_rn(sum);
            const float w   = (tv == 0) ? a0 : ((tv == 1) ? a1 : a2);
            const float om  = 1.0f - pt;
            const float focal = w * om * om * ce;
            const bool  m   = (mw >> ((j0 & 63) + j)) & 1ULL;

            fsum_a += focal;
            fsum_m += m ? focal : 0.0f;
            cnt_m  += m ? 1 : 0;
        }
        c0 = n0; c1 = n1; c2 = n2;
    }

    // ---- block reduce + ONE plain store per block (no atomics) ----
    const int wave = t >> 6, lane = t & 63;
    #pragma unroll
    for (int off = 32; off >= 1; off >>= 1) {
        fsum_m += __shfl_down(fsum_m, off);
        fsum_a += __shfl_down(fsum_a, off);
        cnt_m  += __shfl_down(cnt_m, off);
        cnt_p  += __shfl_down(cnt_p, off);
    }
    if (lane == 0) {
        red[wave*4]   = (double)fsum_m; red[wave*4+1] = (double)cnt_m;
        red[wave*4+2] = (double)fsum_a; red[wave*4+3] = (double)cnt_p;
    }
    __syncthreads();
    if (t == 0) {
        double sm = 0, sc = 0, sa = 0, sp = 0;
        #pragma unroll
        for (int w = 0; w < NTHREADS/64; ++w) {
            sm += red[w*4]; sc += red[w*4+1]; sa += red[w*4+2]; sp += red[w*4+3];
        }
        double* slot = slots + (long)blockIdx.x * 4;
        slot[0] = sm;
        slot[1] = sc;
        slot[2] = sa;
        slot[3] = sp;
    }
}

__global__ __launch_bounds__(NTHREADS) void focal_final(
    const double* __restrict__ slots, float* __restrict__ out)
{
    __shared__ double red[(NTHREADS/64) * 2];
    __shared__ double tot[2];
    const int t = threadIdx.x;
    const int wave = t >> 6, lane = t & 63;

    // Phase A: global masked sum/count over all 2048 slots
    double sm = 0.0, sc = 0.0;
    for (int k = t; k < NBLOCKS; k += NTHREADS) {
        sm += slots[(long)k * 4 + 0];
        sc += slots[(long)k * 4 + 1];
    }
    #pragma unroll
    for (int off = 32; off >= 1; off >>= 1) {
        sm += __shfl_down(sm, off);
        sc += __shfl_down(sc, off);
    }
    if (lane == 0) { red[wave*2] = sm; red[wave*2+1] = sc; }
    __syncthreads();
    if (t == 0) {
        double a = 0, b = 0;
        #pragma unroll
        for (int w = 0; w < NTHREADS/64; ++w) { a += red[w*2]; b += red[w*2+1]; }
        tot[0] = a; tot[1] = b;
    }
    __syncthreads();

    // Phase B: per-row "no positives" correction (wave 0, thread t = row t)
    double corr_s = 0.0, corr_c = 0.0;
    if (t < BB) {
        double row_sum = 0.0, row_pos = 0.0;
        for (int j = 0; j < TILES_PER_ROW; ++j) {
            const long blk = (long)t * TILES_PER_ROW + j;
            row_sum += slots[blk * 4 + 2];
            row_pos += slots[blk * 4 + 3];
        }
        if (row_pos == 0.0) { corr_s = row_sum; corr_c = (double)SS; }
    }
    if (wave == 0) {
        #pragma unroll
        for (int off = 32; off >= 1; off >>= 1) {
            corr_s += __shfl_down(corr_s, off);
            corr_c += __shfl_down(corr_c, off);
        }
        if (t == 0) {
            const double total = tot[0] + corr_s;
            const double count = tot[1] + corr_c;
            out[0] = (float)(total / count);
        }
    }
}

extern "C" void kernel_launch(void* const* d_in, const int* in_sizes, int n_in,
                              void* d_out, int out_size, void* d_ws, size_t ws_size,
                              hipStream_t stream) {
    const float* inputs  = (const float*)d_in[0];
    const int*   targets = (const int*)d_in[1];
    const float* alpha   = (const float*)d_in[2];
    float* out = (float*)d_out;

    double* slots = (double*)d_ws;   // NBLOCKS * 4 doubles = 64 KB, all written

    focal_main<<<NBLOCKS, NTHREADS, 0, stream>>>(inputs, targets, alpha, slots);
    focal_final<<<1, NTHREADS, 0, stream>>>(slots, out);
}